// Round 6
// baseline (361.965 us; speedup 1.0000x reference)
//
#include <hip/hip_runtime.h>
#include <float.h>
#include <stdint.h>

// Chamfer distance via MFMA (bf16 hi/lo compensated split), round 6.
// d[n][m] = ||t_m||^2 - 2 q_n . t_m  + ||q_n||^2 (added in epilogue)
// One mfma_f32_32x32x16_bf16 computes a 32q x 32t tile of (tt - 2q.t):
//   A k-slots (query row, c = -2q): [chx chy chz clx cly clz chx chy |
//                                    chz 1 1 clx cly clz 0 0]
//   B k-slots (target col):         [bhx bhy bhz bhx bhy bhz blx bly |
//                                    blz tth ttl blx bly blz 0 0]
// B fragments prepacked by prep_kernel into ws (8 MB): H0 region = lanes
// 0-31 (k=0..7), H1 region = lanes 32-63 (k=8..15).
// Main loop: one-pair-ahead prefetch -> 4x mfma -> fminf(fminf) fold
// (compiler emits v_min3 and models MFMA hazards; NO inline asm on MFMA
// results -- that was R5's corruption). Last iteration peeled (no OOB).
// Epilogue: R4-verified LDS matrix path.

typedef short bf16x8 __attribute__((ext_vector_type(8)));
typedef float f32x16 __attribute__((ext_vector_type(16)));

#define BLK 256
#define ONE_BF 0x3F80u

__device__ __forceinline__ uint32_t bf16_rne(float f) {
    uint32_t u = __builtin_bit_cast(uint32_t, f);
    return (u + 0x7FFFu + ((u >> 16) & 1u)) >> 16;
}
__device__ __forceinline__ float bf16f(uint32_t h) {
    return __builtin_bit_cast(float, h << 16);
}

// ---- prep: 262144 points (arr0 = x, arr1 = recon), 16B H0 + 16B H1 each.
__global__ __launch_bounds__(BLK)
void prep_kernel(const float* __restrict__ x, const float* __restrict__ recon,
                 uint32_t* __restrict__ ws)
{
    int tid = blockIdx.x * BLK + threadIdx.x;     // 0..262143
    int arr = tid >> 17;
    int p   = tid & 131071;
    const float* s = arr ? recon : x;
    float a = s[3 * p], b = s[3 * p + 1], c = s[3 * p + 2];
    uint32_t hx = bf16_rne(a), hy = bf16_rne(b), hz = bf16_rne(c);
    uint32_t lx = bf16_rne(a - bf16f(hx));
    uint32_t ly = bf16_rne(b - bf16f(hy));
    uint32_t lz = bf16_rne(c - bf16f(hz));
    float tt = a * a + b * b + c * c;
    uint32_t th = bf16_rne(tt);
    uint32_t tl = bf16_rne(tt - bf16f(th));
    uint4 H0 = make_uint4(hx | (hy << 16), hz | (hx << 16),
                          hy | (hz << 16), lx | (ly << 16));
    uint4 H1 = make_uint4(lz | (th << 16), tl | (lx << 16),
                          ly | (lz << 16), 0u);
    ((uint4*)ws)[tid]          = H0;
    ((uint4*)ws)[262144 + tid] = H1;
}

// ---- main: 1024 blocks (XCD-swizzled), 256 thr = 4 waves.
// Wave owns 64 queries (2 x 32-row MFMA A-blocks), loops all 4096 targets.
__global__ __launch_bounds__(BLK, 4)
void chamfer_mfma(const float* __restrict__ x, const float* __restrict__ recon,
                  const uint32_t* __restrict__ ws, float* __restrict__ out,
                  float scale)
{
    // XCD-aware decode: XCD k owns contiguous (dir,b) target slices.
    int idx = blockIdx.x;
    int swz = (idx & 7) * 128 + (idx >> 3);       // bijective, 1024 % 8 == 0
    int dir = swz >> 9;
    int b   = (swz >> 4) & 31;
    int qb  = swz & 15;

    const float* qsrc = dir ? recon : x;          // queries
    const int arrT = dir ? 0 : 1;                 // targets = other array

    const int tid  = threadIdx.x;
    const int wave = tid >> 6;
    const int lane = tid & 63;
    const int l31  = lane & 31;
    const int lh   = lane >> 5;

    // A fragments (one-time): row = l31 within each 32-row block.
    bf16x8 A0, A1;
    {
        int n0 = qb * 256 + wave * 64 + l31;
        #pragma unroll
        for (int rb = 0; rb < 2; ++rb) {
            const float* qp = qsrc + ((size_t)b * 4096 + n0 + rb * 32) * 3;
            float cx = -2.f * qp[0], cy = -2.f * qp[1], cz = -2.f * qp[2];
            uint32_t hx = bf16_rne(cx), hy = bf16_rne(cy), hz = bf16_rne(cz);
            uint32_t lx = bf16_rne(cx - bf16f(hx));
            uint32_t ly = bf16_rne(cy - bf16f(hy));
            uint32_t lz = bf16_rne(cz - bf16f(hz));
            uint32_t w0, w1, w2, w3;
            if (lh == 0) {
                w0 = hx | (hy << 16); w1 = hz | (lx << 16);
                w2 = ly | (lz << 16); w3 = hx | (hy << 16);
            } else {
                w0 = hz | (ONE_BF << 16); w1 = ONE_BF | (lx << 16);
                w2 = ly | (lz << 16);     w3 = 0u;
            }
            union { uint4 u; bf16x8 v; } cvt;
            cvt.u = make_uint4(w0, w1, w2, w3);
            if (rb == 0) A0 = cvt.v; else A1 = cvt.v;
        }
    }

    f32x16 zc = {0,0,0,0,0,0,0,0,0,0,0,0,0,0,0,0};
    float rmn0[16], rmn1[16];
    #pragma unroll
    for (int j = 0; j < 16; ++j) { rmn0[j] = FLT_MAX; rmn1[j] = FLT_MAX; }

    // B-fragment stream: lane half picks H0/H1 region; col = l31.
    const uint4* rec = (const uint4*)ws
        + (size_t)lh * 262144 + (size_t)arrT * 131072 + (size_t)b * 4096 + l31;

    union BU { uint4 u; bf16x8 v; };
    BU c0, c1, n0v, n1v;
    c0.u = rec[0]; c1.u = rec[32];
    const uint4* rp = rec + 64;

    // 63 pipelined pair-iterations (tiles 0..125 computed, prefetch up to
    // tile 127) + peeled tail for tiles 126,127. All reads in-bounds.
    #pragma unroll 2
    for (int p = 0; p < 63; ++p) {
        n0v.u = rp[0];
        n1v.u = rp[32];
        f32x16 d00 = __builtin_amdgcn_mfma_f32_32x32x16_bf16(A0, c0.v, zc, 0, 0, 0);
        f32x16 d10 = __builtin_amdgcn_mfma_f32_32x32x16_bf16(A1, c0.v, zc, 0, 0, 0);
        f32x16 d01 = __builtin_amdgcn_mfma_f32_32x32x16_bf16(A0, c1.v, zc, 0, 0, 0);
        f32x16 d11 = __builtin_amdgcn_mfma_f32_32x32x16_bf16(A1, c1.v, zc, 0, 0, 0);
        #pragma unroll
        for (int j = 0; j < 16; ++j) {
            rmn0[j] = fminf(rmn0[j], fminf(d00[j], d01[j]));
            rmn1[j] = fminf(rmn1[j], fminf(d10[j], d11[j]));
        }
        c0 = n0v; c1 = n1v; rp += 64;
    }
    {   // tail: tiles 126,127 (no prefetch)
        f32x16 d00 = __builtin_amdgcn_mfma_f32_32x32x16_bf16(A0, c0.v, zc, 0, 0, 0);
        f32x16 d10 = __builtin_amdgcn_mfma_f32_32x32x16_bf16(A1, c0.v, zc, 0, 0, 0);
        f32x16 d01 = __builtin_amdgcn_mfma_f32_32x32x16_bf16(A0, c1.v, zc, 0, 0, 0);
        f32x16 d11 = __builtin_amdgcn_mfma_f32_32x32x16_bf16(A1, c1.v, zc, 0, 0, 0);
        #pragma unroll
        for (int j = 0; j < 16; ++j) {
            rmn0[j] = fminf(rmn0[j], fminf(d00[j], d01[j]));
            rmn1[j] = fminf(rmn1[j], fminf(d10[j], d11[j]));
        }
    }

    // Epilogue (R4-verified): per-query min across 32 cols via LDS,
    // +||q||^2, block sum, one atomicAdd.
    __shared__ float lmin[256][33];
    #pragma unroll
    for (int j = 0; j < 16; ++j) {
        int rl = (j & 3) + 8 * (j >> 2) + 4 * lh;  // verified 32x32 C/D row
        lmin[wave * 64 + rl][l31]      = rmn0[j];
        lmin[wave * 64 + 32 + rl][l31] = rmn1[j];
    }
    __syncthreads();

    float m = lmin[tid][0];
    #pragma unroll
    for (int c = 1; c < 32; ++c) m = fminf(m, lmin[tid][c]);

    const float* qp = qsrc + ((size_t)b * 4096 + qb * 256 + tid) * 3;
    float v = m + qp[0] * qp[0] + qp[1] * qp[1] + qp[2] * qp[2];

    #pragma unroll
    for (int off = 32; off > 0; off >>= 1)
        v += __shfl_down(v, off, 64);
    __shared__ float red[4];
    if (lane == 0) red[wave] = v;
    __syncthreads();
    if (tid == 0)
        atomicAdd(out, (red[0] + red[1] + red[2] + red[3]) * scale);
}

extern "C" void kernel_launch(void* const* d_in, const int* in_sizes, int n_in,
                              void* d_out, int out_size, void* d_ws, size_t ws_size,
                              hipStream_t stream) {
    const float* x     = (const float*)d_in[0];
    const float* recon = (const float*)d_in[1];
    float* out = (float*)d_out;

    const float scale = 1.0f / (32.0f * 4096.0f);

    hipMemsetAsync(out, 0, sizeof(float), stream);

    prep_kernel<<<1024, BLK, 0, stream>>>(x, recon, (uint32_t*)d_ws);

    chamfer_mfma<<<1024, BLK, 0, stream>>>(x, recon, (const uint32_t*)d_ws,
                                           out, scale);
}

// Round 7
// 100.910 us; speedup vs baseline: 3.5870x; 3.5870x over previous
//
#include <hip/hip_runtime.h>
#include <float.h>
#include <stdint.h>

// Chamfer distance via MFMA (bf16 hi/lo compensated split), round 7.
// d[n][m] = ||t_m||^2 - 2 q_n . t_m  + ||q_n||^2 (added in epilogue)
// One mfma_f32_32x32x16_bf16 computes a 32q x 32t tile of (tt - 2q.t):
//   A k-slots (query row, c = -2q): [chx chy chz clx cly clz chx chy |
//                                    chz 1 1 clx cly clz 0 0]
//   B k-slots (target col):         [bhx bhy bhz bhx bhy bhz blx bly |
//                                    blz tth ttl blx bly blz 0 0]
// B fragments prepacked by prep_kernel into ws (8 MB): H0 region = lanes
// 0-31 (k=0..7), H1 region = lanes 32-63 (k=8..15).
// R7 deltas vs R4 (48.6us proven): A-major paired tiles so mins fold as
// fminf(fminf()) -> v_min3 with only TWO f32x16 MFMA results live (R6's
// four-live version spilled 878 MB/dispatch to scratch);
// __launch_bounds__(256,3) for regalloc headroom; XCD swizzle; out-zeroing
// folded into prep (no memset node). No inline asm on MFMA results (R5).

typedef short bf16x8 __attribute__((ext_vector_type(8)));
typedef float f32x16 __attribute__((ext_vector_type(16)));

#define BLK 256
#define ONE_BF 0x3F80u

__device__ __forceinline__ uint32_t bf16_rne(float f) {
    uint32_t u = __builtin_bit_cast(uint32_t, f);
    return (u + 0x7FFFu + ((u >> 16) & 1u)) >> 16;
}
__device__ __forceinline__ float bf16f(uint32_t h) {
    return __builtin_bit_cast(float, h << 16);
}

// ---- prep: 262144 points (arr0 = x, arr1 = recon), 16B H0 + 16B H1 each.
// Also zeroes the output accumulator (stream-ordered before main kernel).
__global__ __launch_bounds__(BLK)
void prep_kernel(const float* __restrict__ x, const float* __restrict__ recon,
                 uint32_t* __restrict__ ws, float* __restrict__ out)
{
    int tid = blockIdx.x * BLK + threadIdx.x;     // 0..262143
    if (tid == 0) out[0] = 0.0f;
    int arr = tid >> 17;
    int p   = tid & 131071;
    const float* s = arr ? recon : x;
    float a = s[3 * p], b = s[3 * p + 1], c = s[3 * p + 2];
    uint32_t hx = bf16_rne(a), hy = bf16_rne(b), hz = bf16_rne(c);
    uint32_t lx = bf16_rne(a - bf16f(hx));
    uint32_t ly = bf16_rne(b - bf16f(hy));
    uint32_t lz = bf16_rne(c - bf16f(hz));
    float tt = a * a + b * b + c * c;
    uint32_t th = bf16_rne(tt);
    uint32_t tl = bf16_rne(tt - bf16f(th));
    uint4 H0 = make_uint4(hx | (hy << 16), hz | (hx << 16),
                          hy | (hz << 16), lx | (ly << 16));
    uint4 H1 = make_uint4(lz | (th << 16), tl | (lx << 16),
                          ly | (lz << 16), 0u);
    ((uint4*)ws)[tid]          = H0;
    ((uint4*)ws)[262144 + tid] = H1;
}

// ---- main: 1024 blocks (XCD-swizzled), 256 thr = 4 waves.
// Wave owns 64 queries (2 x 32-row MFMA A-blocks), loops all 4096 targets.
__global__ __launch_bounds__(BLK, 3)
void chamfer_mfma(const float* __restrict__ x, const float* __restrict__ recon,
                  const uint32_t* __restrict__ ws, float* __restrict__ out,
                  float scale)
{
    // XCD-aware decode: XCD k owns contiguous (dir,b) target slices.
    int idx = blockIdx.x;
    int swz = (idx & 7) * 128 + (idx >> 3);       // bijective, 1024 % 8 == 0
    int dir = swz >> 9;
    int b   = (swz >> 4) & 31;
    int qb  = swz & 15;

    const float* qsrc = dir ? recon : x;          // queries
    const int arrT = dir ? 0 : 1;                 // targets = other array

    const int tid  = threadIdx.x;
    const int wave = tid >> 6;
    const int lane = tid & 63;
    const int l31  = lane & 31;
    const int lh   = lane >> 5;

    // A fragments (one-time): row = l31 within each 32-row block.
    bf16x8 A0, A1;
    {
        int n0 = qb * 256 + wave * 64 + l31;
        #pragma unroll
        for (int rb = 0; rb < 2; ++rb) {
            const float* qp = qsrc + ((size_t)b * 4096 + n0 + rb * 32) * 3;
            float cx = -2.f * qp[0], cy = -2.f * qp[1], cz = -2.f * qp[2];
            uint32_t hx = bf16_rne(cx), hy = bf16_rne(cy), hz = bf16_rne(cz);
            uint32_t lx = bf16_rne(cx - bf16f(hx));
            uint32_t ly = bf16_rne(cy - bf16f(hy));
            uint32_t lz = bf16_rne(cz - bf16f(hz));
            uint32_t w0, w1, w2, w3;
            if (lh == 0) {
                w0 = hx | (hy << 16); w1 = hz | (lx << 16);
                w2 = ly | (lz << 16); w3 = hx | (hy << 16);
            } else {
                w0 = hz | (ONE_BF << 16); w1 = ONE_BF | (lx << 16);
                w2 = ly | (lz << 16);     w3 = 0u;
            }
            union { uint4 u; bf16x8 v; } cvt;
            cvt.u = make_uint4(w0, w1, w2, w3);
            if (rb == 0) A0 = cvt.v; else A1 = cvt.v;
        }
    }

    f32x16 zc = {0,0,0,0,0,0,0,0,0,0,0,0,0,0,0,0};
    float rmn0[16], rmn1[16];
    #pragma unroll
    for (int j = 0; j < 16; ++j) { rmn0[j] = FLT_MAX; rmn1[j] = FLT_MAX; }

    // B-fragment stream: lane half picks H0/H1 region; col = l31.
    const uint4* rp = (const uint4*)ws
        + (size_t)lh * 262144 + (size_t)arrT * 131072 + (size_t)b * 4096 + l31;

    // 64 iterations x 2 target-tiles. A-major ordering: only two f32x16
    // MFMA results live at a time (d0,d1 then e0,e1) -> no spills.
    for (int it = 0; it < 64; ++it) {
        union BU { uint4 u; bf16x8 v; } B0, B1;
        B0.u = rp[0];
        B1.u = rp[32];
        rp += 64;
        f32x16 d0 = __builtin_amdgcn_mfma_f32_32x32x16_bf16(A0, B0.v, zc, 0, 0, 0);
        f32x16 d1 = __builtin_amdgcn_mfma_f32_32x32x16_bf16(A0, B1.v, zc, 0, 0, 0);
        #pragma unroll
        for (int j = 0; j < 16; ++j)
            rmn0[j] = fminf(rmn0[j], fminf(d0[j], d1[j]));
        f32x16 e0 = __builtin_amdgcn_mfma_f32_32x32x16_bf16(A1, B0.v, zc, 0, 0, 0);
        f32x16 e1 = __builtin_amdgcn_mfma_f32_32x32x16_bf16(A1, B1.v, zc, 0, 0, 0);
        #pragma unroll
        for (int j = 0; j < 16; ++j)
            rmn1[j] = fminf(rmn1[j], fminf(e0[j], e1[j]));
    }

    // Epilogue (R4-verified): per-query min across 32 cols via LDS,
    // +||q||^2, block sum, one atomicAdd.
    __shared__ float lmin[256][33];
    #pragma unroll
    for (int j = 0; j < 16; ++j) {
        int rl = (j & 3) + 8 * (j >> 2) + 4 * lh;  // verified 32x32 C/D row
        lmin[wave * 64 + rl][l31]      = rmn0[j];
        lmin[wave * 64 + 32 + rl][l31] = rmn1[j];
    }
    __syncthreads();

    float m = lmin[tid][0];
    #pragma unroll
    for (int c = 1; c < 32; ++c) m = fminf(m, lmin[tid][c]);

    const float* qp = qsrc + ((size_t)b * 4096 + qb * 256 + tid) * 3;
    float v = m + qp[0] * qp[0] + qp[1] * qp[1] + qp[2] * qp[2];

    #pragma unroll
    for (int off = 32; off > 0; off >>= 1)
        v += __shfl_down(v, off, 64);
    __shared__ float red[4];
    if (lane == 0) red[wave] = v;
    __syncthreads();
    if (tid == 0)
        atomicAdd(out, (red[0] + red[1] + red[2] + red[3]) * scale);
}

extern "C" void kernel_launch(void* const* d_in, const int* in_sizes, int n_in,
                              void* d_out, int out_size, void* d_ws, size_t ws_size,
                              hipStream_t stream) {
    const float* x     = (const float*)d_in[0];
    const float* recon = (const float*)d_in[1];
    float* out = (float*)d_out;

    const float scale = 1.0f / (32.0f * 4096.0f);

    prep_kernel<<<1024, BLK, 0, stream>>>(x, recon, (uint32_t*)d_ws, out);

    chamfer_mfma<<<1024, BLK, 0, stream>>>(x, recon, (const uint32_t*)d_ws,
                                           out, scale);
}